// Round 1
// baseline (538.985 us; speedup 1.0000x reference)
//
#include <hip/hip_runtime.h>

// ---------------------------------------------------------------------------
// TBasisLayerBase: tensor-ring decompression of an 8192x8192 f32 weight.
//
// Structure:
//   cores[m] (8,4,8) = (bw @ basis) * ra            m = 0..12
//   L = chain(cores[0..5])  -> (8, 4^6=4096, 8)
//   R = chain(cores[6..12]) -> (8, 4^7=16384, 8)
//   w2d[i,j] = sum_{a,b} L[a,i,b] R[b,j,a]
//   out[row,col] = w2d[i,j] with i = interleave6(row>>7, col>>7),
//                               j = interleave7(row&127, col&127)
//   (row bits -> odd bit positions, col bits -> even bit positions)
//
// Fused form: out[row,col] = dot64( A[rh][ch][:], B[:][rl][cl] )
//   A (64,64,64)  k-minor : A[rh][ch][a*8+b] = L[a, ilv6(rh,ch), b]
//   B (64,128,128) k-major: B[a*8+b][rl][cl] = R[b, ilv7(rl,cl), a]
// ---------------------------------------------------------------------------

#define WS_CORES 0        //  3328 f : cores[13][8][4][8]
#define WS_LA    4096     // 16384 f : (8,256,8)  modes 0-3
#define WS_LB    20480    //  1024 f : (8,16,8)   modes 4-5
#define WS_RA    24576    // 16384 f : (8,256,8)  modes 6-9
#define WS_RB    40960    //  4096 f : (8,64,8)   modes 10-12
#define WS_A     65536    // 262144 f: [rh][ch][k]
#define WS_B     327680   // 1048576f: [k][rl][cl]

// ---- K1: decompress cores -------------------------------------------------
__global__ void k_cores(const float* __restrict__ bw,
                        const float* __restrict__ basis,
                        const float* __restrict__ ra,
                        float* __restrict__ ws) {
    int e = blockIdx.x * 256 + threadIdx.x;     // 13*256 = 3328 total
    if (e >= 13 * 256) return;
    int m    = e >> 8;          // mode
    int r1   = (e >> 5) & 7;    // first rank index
    int rest = e & 255;         // r1*32 + md*8 + r2
    float s = 0.f;
#pragma unroll
    for (int n = 0; n < 32; ++n)
        s = fmaf(bw[m * 32 + n], basis[n * 256 + rest], s);
    ws[WS_CORES + e] = s * ra[m * 8 + r1];
}

// ---- K2: build the four partial chains (one block each) -------------------
__global__ void k_chains(float* __restrict__ ws) {
    __shared__ float sCores[13 * 256];
    __shared__ float buf0[4096];
    __shared__ float buf1[4096];
    const int tid   = threadIdx.x;      // 256 threads
    const int chain = blockIdx.x;       // 0:LA 1:LB 2:RA 3:RB

    const int s0   = (chain == 0) ? 0 : (chain == 1) ? 4 : (chain == 2) ? 6 : 10;
    const int nm   = (chain == 0) ? 4 : (chain == 1) ? 2 : (chain == 2) ? 4 : 3;
    const int wout = (chain == 0) ? WS_LA : (chain == 1) ? WS_LB
                   : (chain == 2) ? WS_RA : WS_RB;

    for (int e = tid; e < 13 * 256; e += 256) sCores[e] = ws[WS_CORES + e];
    __syncthreads();

    const float* src = &sCores[s0 * 256];   // (8, mcur, 8), mcur = 4
    int mcurlog = 2;
    float* dst = buf0;
    for (int step = 1; step < nm; ++step) {
        const float* core = &sCores[(s0 + step) * 256];
        const int moutlog = mcurlog + 2;
        const int mout    = 1 << moutlog;
        const int total   = 64 << moutlog;          // 8*mout*8
        const bool last   = (step == nm - 1);
        for (int e = tid; e < total; e += 256) {
            int b  = e & 7;
            int im = (e >> 3) & (mout - 1);
            int a  = e >> (3 + moutlog);
            int i  = im >> 2, mm = im & 3;
            float s = 0.f;
#pragma unroll
            for (int c = 0; c < 8; ++c)
                s = fmaf(src[((a << mcurlog) + i) * 8 + c],
                         core[(c * 4 + mm) * 8 + b], s);
            if (last) ws[wout + e] = s;
            else      dst[e]       = s;
        }
        __syncthreads();
        src = dst;
        dst = (dst == buf0) ? buf1 : buf0;
        mcurlog = moutlog;
    }
}

// bit-interleave: c -> even bit positions, r -> odd bit positions
__device__ __forceinline__ int ilv(int r, int c, int nb) {
    int v = 0;
    for (int t = 0; t < nb; ++t)
        v |= (((c >> t) & 1) << (2 * t)) | (((r >> t) & 1) << (2 * t + 1));
    return v;
}

// ---- K3: build permuted A (k-minor) and B (k-major) -----------------------
__global__ void k_build(float* __restrict__ ws) {
    int e = blockIdx.x * 256 + threadIdx.x;     // 262144 + 1048576 total
    const float* LA = ws + WS_LA;
    const float* LB = ws + WS_LB;
    const float* RA = ws + WS_RA;
    const float* RB = ws + WS_RB;
    if (e < 262144) {
        // A[rh][ch][k], k = a*8+b ; consecutive threads -> consecutive k
        int k = e & 63, ch = (e >> 6) & 63, rh = e >> 12;
        int i  = ilv(rh, ch, 6);
        int iA = i >> 4, iB = i & 15;
        int a = k >> 3, b = k & 7;
        float s = 0.f;
#pragma unroll
        for (int c = 0; c < 8; ++c)
            s = fmaf(LA[(a * 256 + iA) * 8 + c], LB[(c * 16 + iB) * 8 + b], s);
        ws[WS_A + e] = s;
    } else {
        // B[k][rl][cl], k = a*8+b ; consecutive threads -> consecutive cl
        int idx = e - 262144;
        int cl = idx & 127, rl = (idx >> 7) & 127, k = idx >> 14;
        int j  = ilv(rl, cl, 7);
        int jA = j >> 6, jB = j & 63;
        int a = k >> 3, b = k & 7;
        float s = 0.f;
#pragma unroll
        for (int c = 0; c < 8; ++c)
            s = fmaf(RA[(b * 256 + jA) * 8 + c], RB[(c * 64 + jB) * 8 + a], s);
        ws[WS_B + idx] = s;
    }
}

// ---- K4: fused dot64 + z-order scatter (coalesced writes) -----------------
// grid = 1024 blocks x 256 threads.
//   block: p = bid>>4 selects rl pair {2p, 2p+1}; g = bid&15 selects ch range.
//   thread: rl = 2p + tid/128, cl = tid%128  -> holds B[.,rl,cl] in 64 VGPRs.
//   loops rh 0..63 x 4 ch values; A row is wave-uniform -> scalar loads.
__global__ __launch_bounds__(256, 4) void k_out(const float* __restrict__ ws,
                                                float* __restrict__ out) {
    const float* A = ws + WS_A;
    const float* B = ws + WS_B;
    const int tid = threadIdx.x;
    const int bid = blockIdx.x;
    const int g = bid & 15;                 // ch group: ch in [4g, 4g+4)
    const int p = bid >> 4;                 // rl pair
    const int rl = (p << 1) | (tid >> 7);
    const int cl = tid & 127;

    float bv[64];
#pragma unroll
    for (int k = 0; k < 64; ++k)
        bv[k] = B[(k << 14) + (rl << 7) + cl];

    const int rowoff = (rl << 13) + cl;     // rl*8192 + cl

    for (int rh = 0; rh < 64; ++rh) {
#pragma unroll 1
        for (int cc = 0; cc < 4; ++cc) {
            const int ch = (g << 2) | cc;
            const float* __restrict__ a = A + (((rh << 6) | ch) << 6);
            float a0 = 0.f, a1 = 0.f, a2 = 0.f, a3 = 0.f;
#pragma unroll
            for (int k = 0; k < 64; k += 4) {
                a0 = fmaf(a[k + 0], bv[k + 0], a0);
                a1 = fmaf(a[k + 1], bv[k + 1], a1);
                a2 = fmaf(a[k + 2], bv[k + 2], a2);
                a3 = fmaf(a[k + 3], bv[k + 3], a3);
            }
            out[((size_t)rh << 20) + (ch << 7) + rowoff] = (a0 + a1) + (a2 + a3);
        }
    }
}

// ---------------------------------------------------------------------------
extern "C" void kernel_launch(void* const* d_in, const int* in_sizes, int n_in,
                              void* d_out, int out_size, void* d_ws, size_t ws_size,
                              hipStream_t stream) {
    const float* bw    = (const float*)d_in[0];   // (13, 32)
    const float* basis = (const float*)d_in[1];   // (32, 8, 4, 8)
    const float* ra    = (const float*)d_in[2];   // (13, 8)
    float* out = (float*)d_out;                   // (8192, 8192) f32
    float* ws  = (float*)d_ws;                    // needs ~5.5 MB

    k_cores <<<13,   256, 0, stream>>>(bw, basis, ra, ws);
    k_chains<<<4,    256, 0, stream>>>(ws);
    k_build <<<5120, 256, 0, stream>>>(ws);
    k_out   <<<1024, 256, 0, stream>>>(ws, out);
}

// Round 2
// 164.032 us; speedup vs baseline: 3.2859x; 3.2859x over previous
//
#include <hip/hip_runtime.h>

// ---------------------------------------------------------------------------
// TBasisLayerBase: tensor-ring decompression of an 8192x8192 f32 weight.
//
//   cores[m] (8,4,8) = (bw @ basis) * ra            m = 0..12
//   L = chain(cores[0..5])  -> (8, 4096, 8) ;  R = chain(cores[6..12]) -> (8, 16384, 8)
//   w2d[i,j] = sum_{a,b} L[a,i,b] R[b,j,a]
//   out[row,col] = w2d[ilv6(row>>7,col>>7), ilv7(row&127,col&127)]
//
// GEMM form:  G[m][n] = A2[m][k] * B2t[n][k],  m=(rh,ch) 4096, n=(rl,cl) 16384, k=64
//   out[rh*128+rl][ch*128+cl] = G[rh*64+ch][rl*128+cl]
// Split-bf16 (hi+lo) MFMA keeps f32-level accuracy:
//   G = Ahi*Bhi + Ahi*Blo + Alo*Bhi   (lo*lo term ~2^-18, dropped)
// ---------------------------------------------------------------------------

using bf16x8 = __attribute__((ext_vector_type(8))) short;
using f32x4  = __attribute__((ext_vector_type(4))) float;

// f32 scratch (float offsets)
#define WS_CORES 0        //  3328 f : cores[13][8][4][8]
#define WS_LA    4096     // 16384 f : (8,256,8)  modes 0-3
#define WS_LB    20480    //  1024 f : (8,16,8)   modes 4-5
#define WS_RA    24576    // 16384 f : (8,256,8)  modes 6-9
#define WS_RB    40960    //  4096 f : (8,64,8)   modes 10-12
// bf16 region (byte offsets from ws base) — total footprint 5,505,024 B
#define BOFF_AHI 262144   // [4096][64]  ushort
#define BOFF_ALO 786432
#define BOFF_BHI 1310720  // [16384][64] ushort
#define BOFF_BLO 3407872

__device__ __forceinline__ unsigned short f2bf(float x) {
    unsigned int u = __builtin_bit_cast(unsigned int, x);
    u += 0x7fffu + ((u >> 16) & 1u);          // round-to-nearest-even
    return (unsigned short)(u >> 16);
}
__device__ __forceinline__ float bf2f(unsigned short b) {
    unsigned int u = ((unsigned int)b) << 16;
    return __builtin_bit_cast(float, u);
}

// ---- K1: decompress cores -------------------------------------------------
__global__ void k_cores(const float* __restrict__ bw,
                        const float* __restrict__ basis,
                        const float* __restrict__ ra,
                        float* __restrict__ ws) {
    int e = blockIdx.x * 256 + threadIdx.x;     // 13*256 = 3328 total
    if (e >= 13 * 256) return;
    int m    = e >> 8;
    int r1   = (e >> 5) & 7;
    int rest = e & 255;
    float s = 0.f;
#pragma unroll
    for (int n = 0; n < 32; ++n)
        s = fmaf(bw[m * 32 + n], basis[n * 256 + rest], s);
    ws[WS_CORES + e] = s * ra[m * 8 + r1];
}

// ---- K2: build the four partial chains (one block each) -------------------
__global__ void k_chains(float* __restrict__ ws) {
    __shared__ float sCores[13 * 256];
    __shared__ float buf0[4096];
    __shared__ float buf1[4096];
    const int tid   = threadIdx.x;      // 256 threads
    const int chain = blockIdx.x;       // 0:LA 1:LB 2:RA 3:RB

    const int s0   = (chain == 0) ? 0 : (chain == 1) ? 4 : (chain == 2) ? 6 : 10;
    const int nm   = (chain == 0) ? 4 : (chain == 1) ? 2 : (chain == 2) ? 4 : 3;
    const int wout = (chain == 0) ? WS_LA : (chain == 1) ? WS_LB
                   : (chain == 2) ? WS_RA : WS_RB;

    for (int e = tid; e < 13 * 256; e += 256) sCores[e] = ws[WS_CORES + e];
    __syncthreads();

    const float* src = &sCores[s0 * 256];
    int mcurlog = 2;
    float* dst = buf0;
    for (int step = 1; step < nm; ++step) {
        const float* core = &sCores[(s0 + step) * 256];
        const int moutlog = mcurlog + 2;
        const int mout    = 1 << moutlog;
        const int total   = 64 << moutlog;
        const bool last   = (step == nm - 1);
        for (int e = tid; e < total; e += 256) {
            int b  = e & 7;
            int im = (e >> 3) & (mout - 1);
            int a  = e >> (3 + moutlog);
            int i  = im >> 2, mm = im & 3;
            float s = 0.f;
#pragma unroll
            for (int c = 0; c < 8; ++c)
                s = fmaf(src[((a << mcurlog) + i) * 8 + c],
                         core[(c * 4 + mm) * 8 + b], s);
            if (last) ws[wout + e] = s;
            else      dst[e]       = s;
        }
        __syncthreads();
        src = dst;
        dst = (dst == buf0) ? buf1 : buf0;
        mcurlog = moutlog;
    }
}

// bit-interleave: c -> even bit positions, r -> odd bit positions
__device__ __forceinline__ int ilv(int r, int c, int nb) {
    int v = 0;
    for (int t = 0; t < nb; ++t)
        v |= (((c >> t) & 1) << (2 * t)) | (((r >> t) & 1) << (2 * t + 1));
    return v;
}

// ---- K3: build permuted A2 [m][k] and B2t [n][k], split bf16 hi/lo --------
__global__ void k_build(float* __restrict__ ws) {
    int e = blockIdx.x * 256 + threadIdx.x;     // 262144 + 1048576 total
    const float* LA = ws + WS_LA;
    const float* LB = ws + WS_LB;
    const float* RA = ws + WS_RA;
    const float* RB = ws + WS_RB;
    char* wsb = (char*)ws;
    unsigned short* Ahi = (unsigned short*)(wsb + BOFF_AHI);
    unsigned short* Alo = (unsigned short*)(wsb + BOFF_ALO);
    unsigned short* Bhi = (unsigned short*)(wsb + BOFF_BHI);
    unsigned short* Blo = (unsigned short*)(wsb + BOFF_BLO);

    if (e < 262144) {
        // A2[m=(rh,ch)][k], k fastest
        int k = e & 63, ch = (e >> 6) & 63, rh = e >> 12;
        int i  = ilv(rh, ch, 6);
        int iA = i >> 4, iB = i & 15;
        int a = k >> 3, b = k & 7;
        float s = 0.f;
#pragma unroll
        for (int c = 0; c < 8; ++c)
            s = fmaf(LA[(a * 256 + iA) * 8 + c], LB[(c * 16 + iB) * 8 + b], s);
        unsigned short h = f2bf(s);
        Ahi[e] = h;
        Alo[e] = f2bf(s - bf2f(h));
    } else {
        // B2t[n=(rl,cl)][k], k fastest
        int idx = e - 262144;
        int k = idx & 63, n = idx >> 6;
        int rl = n >> 7, cl = n & 127;
        int j  = ilv(rl, cl, 7);
        int jA = j >> 6, jB = j & 63;
        int a = k >> 3, b = k & 7;
        float s = 0.f;
#pragma unroll
        for (int c = 0; c < 8; ++c)
            s = fmaf(RA[(b * 256 + jA) * 8 + c], RB[(c * 64 + jB) * 8 + a], s);
        unsigned short h = f2bf(s);
        Bhi[idx] = h;
        Blo[idx] = f2bf(s - bf2f(h));
    }
}

// ---- K4: MFMA GEMM + z-order tile store -----------------------------------
// grid 4096 = 64 m-blocks x 64 n-blocks. Block: 4 waves; wave w owns m-rows
// [mb*64 + w*16, +16), n range [nb*256, +256) as 16 tiles of 16.
// Fragment layout (16x16x32 bf16): operand idx = lane&15, k = 8*(lane>>4)+j;
// D: col = lane&15, row = (lane>>4)*4 + reg.
__global__ __launch_bounds__(256) void k_mfma(const float* __restrict__ ws,
                                              float* __restrict__ out) {
    const char* wsb = (const char*)ws;
    const unsigned short* Ahi = (const unsigned short*)(wsb + BOFF_AHI);
    const unsigned short* Alo = (const unsigned short*)(wsb + BOFF_ALO);
    const unsigned short* Bhi = (const unsigned short*)(wsb + BOFF_BHI);
    const unsigned short* Blo = (const unsigned short*)(wsb + BOFF_BLO);

    const int tid  = threadIdx.x;
    const int lane = tid & 63;
    const int w    = tid >> 6;
    const int bid  = blockIdx.x;
    const int mb   = bid >> 6;
    const int nb   = bid & 63;
    const int l15  = lane & 15;
    const int lg   = lane >> 4;

    // A fragments for this wave's 16 m-rows (reused across all 16 n-tiles)
    const int mrow = mb * 64 + w * 16 + l15;
    const bf16x8 ahi0 = *(const bf16x8*)(Ahi + mrow * 64 +      lg * 8);
    const bf16x8 ahi1 = *(const bf16x8*)(Ahi + mrow * 64 + 32 + lg * 8);
    const bf16x8 alo0 = *(const bf16x8*)(Alo + mrow * 64 +      lg * 8);
    const bf16x8 alo1 = *(const bf16x8*)(Alo + mrow * 64 + 32 + lg * 8);

#pragma unroll 1
    for (int nt = 0; nt < 16; ++nt) {
        const int n = nb * 256 + nt * 16 + l15;
        const bf16x8 bhi0 = *(const bf16x8*)(Bhi + n * 64 +      lg * 8);
        const bf16x8 bhi1 = *(const bf16x8*)(Bhi + n * 64 + 32 + lg * 8);
        const bf16x8 blo0 = *(const bf16x8*)(Blo + n * 64 +      lg * 8);
        const bf16x8 blo1 = *(const bf16x8*)(Blo + n * 64 + 32 + lg * 8);

        f32x4 acc = {0.f, 0.f, 0.f, 0.f};
        acc = __builtin_amdgcn_mfma_f32_16x16x32_bf16(ahi0, bhi0, acc, 0, 0, 0);
        acc = __builtin_amdgcn_mfma_f32_16x16x32_bf16(ahi1, bhi1, acc, 0, 0, 0);
        acc = __builtin_amdgcn_mfma_f32_16x16x32_bf16(ahi0, blo0, acc, 0, 0, 0);
        acc = __builtin_amdgcn_mfma_f32_16x16x32_bf16(ahi1, blo1, acc, 0, 0, 0);
        acc = __builtin_amdgcn_mfma_f32_16x16x32_bf16(alo0, bhi0, acc, 0, 0, 0);
        acc = __builtin_amdgcn_mfma_f32_16x16x32_bf16(alo1, bhi1, acc, 0, 0, 0);

        // store: m = mb*64 + w*16 + lg*4 + r  -> rh = mb, ch = m&63
        //        n = nb*256 + nt*16 + l15     -> rl = n>>7, cl = n&127
        const int rl     = nb * 2 + (nt >> 3);
        const int clbase = (nt & 7) * 16 + l15;
        const size_t base = ((size_t)mb << 20) + ((size_t)rl << 13) + clbase;
#pragma unroll
        for (int r = 0; r < 4; ++r) {
            const int ch = w * 16 + lg * 4 + r;
            out[base + ((size_t)ch << 7)] = acc[r];
        }
    }
}

// ---------------------------------------------------------------------------
extern "C" void kernel_launch(void* const* d_in, const int* in_sizes, int n_in,
                              void* d_out, int out_size, void* d_ws, size_t ws_size,
                              hipStream_t stream) {
    const float* bw    = (const float*)d_in[0];   // (13, 32)
    const float* basis = (const float*)d_in[1];   // (32, 8, 4, 8)
    const float* ra    = (const float*)d_in[2];   // (13, 8)
    float* out = (float*)d_out;                   // (8192, 8192) f32
    float* ws  = (float*)d_ws;

    k_cores <<<13,   256, 0, stream>>>(bw, basis, ra, ws);
    k_chains<<<4,    256, 0, stream>>>(ws);
    k_build <<<5120, 256, 0, stream>>>(ws);
    k_mfma  <<<4096, 256, 0, stream>>>(ws, out);
}

// Round 3
// 102.782 us; speedup vs baseline: 5.2439x; 1.5959x over previous
//
#include <hip/hip_runtime.h>

// ---------------------------------------------------------------------------
// TBasisLayerBase: tensor-ring decompression of an 8192x8192 f32 weight.
//
//   cores[m] (8,4,8) = (bw @ basis) * ra            m = 0..12
//   L = chain(cores[0..5])  -> (8, 4096, 8) ;  R = chain(cores[6..12]) -> (8, 16384, 8)
//   w2d[i,j] = sum_{a,b} L[a,i,b] R[b,j,a]
//   out[row,col] = w2d[ilv6(row>>7,col>>7), ilv7(row&127,col&127)]
//
// GEMM form:  G[m][n] = A2[m][k] * B2t[n][k],  m=(rh,ch) 4096, n=(rl,cl) 16384, k=64
//   out[rh*128+rl][ch*128+cl] = G[rh*64+ch][rl*128+cl]
// Split-bf16 (hi+lo) MFMA keeps f32-level accuracy:
//   G = Ahi*Bhi + Ahi*Blo + Alo*Bhi   (lo*lo term ~2^-18, dropped)
//
// k_out2: block=(mb,nb) -> out rows {mb*128+nb*2, +1}, all 8192 cols.
//   Waves split n-tiles; all 4 A-tile fragment sets live in registers.
//   Accs staged in 32-KB LDS row image (XOR-swizzled), then streamed out as
//   contiguous dwordx4 -> full-line writes, no write-allocate.
// ---------------------------------------------------------------------------

using bf16x8 = __attribute__((ext_vector_type(8))) short;
using f32x4  = __attribute__((ext_vector_type(4))) float;

// f32 scratch (float offsets)
#define WS_CORES 0        // (unused scratch slot)
#define WS_LA    4096     // 16384 f : (8,256,8)  modes 0-3
#define WS_LB    20480    //  1024 f : (8,16,8)   modes 4-5
#define WS_RA    24576    // 16384 f : (8,256,8)  modes 6-9
#define WS_RB    40960    //  4096 f : (8,64,8)   modes 10-12
// bf16 region (byte offsets from ws base)
#define BOFF_AHI 262144   // [4096][64]  ushort
#define BOFF_ALO 786432
#define BOFF_BHI 1310720  // [16384][64] ushort
#define BOFF_BLO 3407872

__device__ __forceinline__ unsigned short f2bf(float x) {
    unsigned int u = __builtin_bit_cast(unsigned int, x);
    u += 0x7fffu + ((u >> 16) & 1u);          // round-to-nearest-even
    return (unsigned short)(u >> 16);
}
__device__ __forceinline__ float bf2f(unsigned short b) {
    unsigned int u = ((unsigned int)b) << 16;
    return __builtin_bit_cast(float, u);
}

// ---- K1: cores + the four partial chains (one block each) -----------------
__global__ void k_chains(const float* __restrict__ bw,
                         const float* __restrict__ basis,
                         const float* __restrict__ ra,
                         float* __restrict__ ws) {
    __shared__ float sCores[13 * 256];
    __shared__ float buf0[4096];
    __shared__ float buf1[4096];
    const int tid   = threadIdx.x;      // 256 threads
    const int chain = blockIdx.x;       // 0:LA 1:LB 2:RA 3:RB

    const int s0   = (chain == 0) ? 0 : (chain == 1) ? 4 : (chain == 2) ? 6 : 10;
    const int nm   = (chain == 0) ? 4 : (chain == 1) ? 2 : (chain == 2) ? 4 : 3;
    const int wout = (chain == 0) ? WS_LA : (chain == 1) ? WS_LB
                   : (chain == 2) ? WS_RA : WS_RB;

    // decompress cores (redundantly per block; trivial)
    for (int e = tid; e < 13 * 256; e += 256) {
        int m    = e >> 8;
        int r1   = (e >> 5) & 7;
        int rest = e & 255;
        float s = 0.f;
#pragma unroll
        for (int n = 0; n < 32; ++n)
            s = fmaf(bw[m * 32 + n], basis[n * 256 + rest], s);
        sCores[e] = s * ra[m * 8 + r1];
    }
    __syncthreads();

    const float* src = &sCores[s0 * 256];
    int mcurlog = 2;
    float* dst = buf0;
    for (int step = 1; step < nm; ++step) {
        const float* core = &sCores[(s0 + step) * 256];
        const int moutlog = mcurlog + 2;
        const int mout    = 1 << moutlog;
        const int total   = 64 << moutlog;
        const bool last   = (step == nm - 1);
        for (int e = tid; e < total; e += 256) {
            int b  = e & 7;
            int im = (e >> 3) & (mout - 1);
            int a  = e >> (3 + moutlog);
            int i  = im >> 2, mm = im & 3;
            float s = 0.f;
#pragma unroll
            for (int c = 0; c < 8; ++c)
                s = fmaf(src[((a << mcurlog) + i) * 8 + c],
                         core[(c * 4 + mm) * 8 + b], s);
            if (last) ws[wout + e] = s;
            else      dst[e]       = s;
        }
        __syncthreads();
        src = dst;
        dst = (dst == buf0) ? buf1 : buf0;
        mcurlog = moutlog;
    }
}

// bit-interleave: c -> even bit positions, r -> odd bit positions
__device__ __forceinline__ int ilv(int r, int c, int nb) {
    int v = 0;
    for (int t = 0; t < nb; ++t)
        v |= (((c >> t) & 1) << (2 * t)) | (((r >> t) & 1) << (2 * t + 1));
    return v;
}

// ---- K2: build permuted A2 [m][k] and B2t [n][k], split bf16 hi/lo --------
__global__ void k_build(float* __restrict__ ws) {
    int e = blockIdx.x * 256 + threadIdx.x;     // 262144 + 1048576 total
    const float* LA = ws + WS_LA;
    const float* LB = ws + WS_LB;
    const float* RA = ws + WS_RA;
    const float* RB = ws + WS_RB;
    char* wsb = (char*)ws;
    unsigned short* Ahi = (unsigned short*)(wsb + BOFF_AHI);
    unsigned short* Alo = (unsigned short*)(wsb + BOFF_ALO);
    unsigned short* Bhi = (unsigned short*)(wsb + BOFF_BHI);
    unsigned short* Blo = (unsigned short*)(wsb + BOFF_BLO);

    if (e < 262144) {
        int k = e & 63, ch = (e >> 6) & 63, rh = e >> 12;
        int i  = ilv(rh, ch, 6);
        int iA = i >> 4, iB = i & 15;
        int a = k >> 3, b = k & 7;
        float s = 0.f;
#pragma unroll
        for (int c = 0; c < 8; ++c)
            s = fmaf(LA[(a * 256 + iA) * 8 + c], LB[(c * 16 + iB) * 8 + b], s);
        unsigned short h = f2bf(s);
        Ahi[e] = h;
        Alo[e] = f2bf(s - bf2f(h));
    } else {
        int idx = e - 262144;
        int k = idx & 63, n = idx >> 6;
        int rl = n >> 7, cl = n & 127;
        int j  = ilv(rl, cl, 7);
        int jA = j >> 6, jB = j & 63;
        int a = k >> 3, b = k & 7;
        float s = 0.f;
#pragma unroll
        for (int c = 0; c < 8; ++c)
            s = fmaf(RA[(b * 256 + jA) * 8 + c], RB[(c * 64 + jB) * 8 + a], s);
        unsigned short h = f2bf(s);
        Bhi[idx] = h;
        Blo[idx] = f2bf(s - bf2f(h));
    }
}

// ---- K3: MFMA GEMM + LDS row stage + coalesced row store -------------------
// grid 4096 = (mb 0..63) x (nb 0..63). Block: 4 waves, 256 threads.
// Wave w handles n-tiles nt = phase*8 + h*4 + w (h=0..1), all 4 ch-tiles.
// Phase p produces out row mb*128 + nb*2 + p (8192 f32, staged in LDS).
__global__ __launch_bounds__(256) void k_out2(const float* __restrict__ ws,
                                              float* __restrict__ out) {
    __shared__ float sOut[8192];        // one output row (32 KB)

    const char* wsb = (const char*)ws;
    const unsigned short* Ahi = (const unsigned short*)(wsb + BOFF_AHI);
    const unsigned short* Alo = (const unsigned short*)(wsb + BOFF_ALO);
    const unsigned short* Bhi = (const unsigned short*)(wsb + BOFF_BHI);
    const unsigned short* Blo = (const unsigned short*)(wsb + BOFF_BLO);

    const int tid  = threadIdx.x;
    const int lane = tid & 63;
    const int w    = tid >> 6;
    const int mb   = blockIdx.x >> 6;
    const int nb   = blockIdx.x & 63;
    const int l15  = lane & 15;
    const int lg   = lane >> 4;

    // All 4 ch-tile A fragment sets in registers (reused for every n-tile).
    bf16x8 ahi[4][2], alo[4][2];
#pragma unroll
    for (int ct = 0; ct < 4; ++ct) {
        const int mrow = mb * 64 + ct * 16 + l15;
#pragma unroll
        for (int hh = 0; hh < 2; ++hh) {
            ahi[ct][hh] = *(const bf16x8*)(Ahi + mrow * 64 + hh * 32 + lg * 8);
            alo[ct][hh] = *(const bf16x8*)(Alo + mrow * 64 + hh * 32 + lg * 8);
        }
    }

#pragma unroll 1
    for (int phase = 0; phase < 2; ++phase) {
#pragma unroll 1
        for (int h = 0; h < 2; ++h) {
            const int nt = phase * 8 + h * 4 + w;
            const int n  = nb * 256 + nt * 16 + l15;
            const bf16x8 bhi0 = *(const bf16x8*)(Bhi + n * 64 +      lg * 8);
            const bf16x8 bhi1 = *(const bf16x8*)(Bhi + n * 64 + 32 + lg * 8);
            const bf16x8 blo0 = *(const bf16x8*)(Blo + n * 64 +      lg * 8);
            const bf16x8 blo1 = *(const bf16x8*)(Blo + n * 64 + 32 + lg * 8);

            f32x4 acc[4];
#pragma unroll
            for (int ct = 0; ct < 4; ++ct) {
                f32x4 a4 = {0.f, 0.f, 0.f, 0.f};
                a4 = __builtin_amdgcn_mfma_f32_16x16x32_bf16(ahi[ct][0], bhi0, a4, 0, 0, 0);
                a4 = __builtin_amdgcn_mfma_f32_16x16x32_bf16(ahi[ct][1], bhi1, a4, 0, 0, 0);
                a4 = __builtin_amdgcn_mfma_f32_16x16x32_bf16(ahi[ct][0], blo0, a4, 0, 0, 0);
                a4 = __builtin_amdgcn_mfma_f32_16x16x32_bf16(ahi[ct][1], blo1, a4, 0, 0, 0);
                a4 = __builtin_amdgcn_mfma_f32_16x16x32_bf16(alo[ct][0], bhi0, a4, 0, 0, 0);
                a4 = __builtin_amdgcn_mfma_f32_16x16x32_bf16(alo[ct][1], bhi1, a4, 0, 0, 0);
                acc[ct] = a4;
            }

            // stage to LDS row image; swizzle bit4 by (c>>9)&1 (== lg&1)
            const int cbase = (h * 4 + w) * 16 + l15;
#pragma unroll
            for (int ct = 0; ct < 4; ++ct) {
#pragma unroll
                for (int r = 0; r < 4; ++r) {
                    const int ch = ct * 16 + lg * 4 + r;
                    const int c  = ch * 128 + cbase;
                    sOut[c ^ (((c >> 9) & 1) << 4)] = acc[ct][r];
                }
            }
        }
        __syncthreads();

        // coalesced readout: 8 x 4KB contiguous dwordx4 stores
        const size_t rowbase = ((size_t)(mb * 128 + nb * 2 + phase)) << 13;
#pragma unroll
        for (int it = 0; it < 8; ++it) {
            const int c    = it * 1024 + tid * 4;
            const int pcol = c ^ (((c >> 9) & 1) << 4);
            *(f32x4*)&out[rowbase + c] = *(const f32x4*)&sOut[pcol];
        }
        __syncthreads();
    }
}

// ---------------------------------------------------------------------------
extern "C" void kernel_launch(void* const* d_in, const int* in_sizes, int n_in,
                              void* d_out, int out_size, void* d_ws, size_t ws_size,
                              hipStream_t stream) {
    const float* bw    = (const float*)d_in[0];   // (13, 32)
    const float* basis = (const float*)d_in[1];   // (32, 8, 4, 8)
    const float* ra    = (const float*)d_in[2];   // (13, 8)
    float* out = (float*)d_out;                   // (8192, 8192) f32
    float* ws  = (float*)d_ws;

    k_chains<<<4,    256, 0, stream>>>(bw, basis, ra, ws);
    k_build <<<5120, 256, 0, stream>>>(ws);
    k_out2  <<<4096, 256, 0, stream>>>(ws, out);
}

// Round 4
// 90.943 us; speedup vs baseline: 5.9266x; 1.1302x over previous
//
#include <hip/hip_runtime.h>

// ---------------------------------------------------------------------------
// TBasisLayerBase: tensor-ring decompression of an 8192x8192 f32 weight.
//
//   cores[m] (8,4,8) = (bw @ basis) * ra            m = 0..12
//   L = chain(cores[0..5])  -> (8, 4096, 8) ;  R = chain(cores[6..12]) -> (8, 16384, 8)
//   w2d[i,j] = sum_{a,b} L[a,i,b] R[b,j,a]
//   out[row,col] = w2d[ilv6(row>>7,col>>7), ilv7(row&127,col&127)]
//
// GEMM form:  G[m][n] = A2[m][k] * B2t[n][k],  m=(rh,ch) 4096, n=(rl,cl) 16384, k=64
//   out[rh*128+rl][ch*128+cl] = G[rh*64+ch][rl*128+cl]
// Split-bf16 (hi+lo) MFMA keeps f32-level accuracy:
//   G = Ahi*Bhi + Ahi*Blo + Alo*Bhi   (lo*lo term ~2^-18, dropped)
//
// k_out3: 32x32x16 MFMA, direct full-line stores (no LDS, no barriers).
//   D layout: col=lane&31, row=(reg&3)+8*(reg>>2)+4*(lane>>5)  [verified]
//   -> per reg, a wave store covers 2 full 128-B lines.
//   Block = 64 m x 512 n. grid 2048 = (mb 0..63) x (nbb 0..31).
//   Wave w: n-tiles nt = i*4+w, i=0..3; both 32-row m-tiles in registers.
// ---------------------------------------------------------------------------

using bf16x8 = __attribute__((ext_vector_type(8))) short;
using f32x4  = __attribute__((ext_vector_type(4))) float;
using f32x16 = __attribute__((ext_vector_type(16))) float;

// f32 scratch (float offsets)
#define WS_LA    4096     // 16384 f : (8,256,8)  modes 0-3
#define WS_LB    20480    //  1024 f : (8,16,8)   modes 4-5
#define WS_RA    24576    // 16384 f : (8,256,8)  modes 6-9
#define WS_RB    40960    //  4096 f : (8,64,8)   modes 10-12
// bf16 region (byte offsets from ws base)
#define BOFF_AHI 262144   // [4096][64]  ushort
#define BOFF_ALO 786432
#define BOFF_BHI 1310720  // [16384][64] ushort
#define BOFF_BLO 3407872

__device__ __forceinline__ unsigned short f2bf(float x) {
    unsigned int u = __builtin_bit_cast(unsigned int, x);
    u += 0x7fffu + ((u >> 16) & 1u);          // round-to-nearest-even
    return (unsigned short)(u >> 16);
}
__device__ __forceinline__ float bf2f(unsigned short b) {
    unsigned int u = ((unsigned int)b) << 16;
    return __builtin_bit_cast(float, u);
}

// ---- K1: cores + the four partial chains (one block each) -----------------
__global__ void k_chains(const float* __restrict__ bw,
                         const float* __restrict__ basis,
                         const float* __restrict__ ra,
                         float* __restrict__ ws) {
    __shared__ float sCores[13 * 256];
    __shared__ float buf0[4096];
    __shared__ float buf1[4096];
    const int tid   = threadIdx.x;      // 256 threads
    const int chain = blockIdx.x;       // 0:LA 1:LB 2:RA 3:RB

    const int s0   = (chain == 0) ? 0 : (chain == 1) ? 4 : (chain == 2) ? 6 : 10;
    const int nm   = (chain == 0) ? 4 : (chain == 1) ? 2 : (chain == 2) ? 4 : 3;
    const int wout = (chain == 0) ? WS_LA : (chain == 1) ? WS_LB
                   : (chain == 2) ? WS_RA : WS_RB;

    for (int e = tid; e < 13 * 256; e += 256) {
        int m    = e >> 8;
        int r1   = (e >> 5) & 7;
        int rest = e & 255;
        float s = 0.f;
#pragma unroll
        for (int n = 0; n < 32; ++n)
            s = fmaf(bw[m * 32 + n], basis[n * 256 + rest], s);
        sCores[e] = s * ra[m * 8 + r1];
    }
    __syncthreads();

    const float* src = &sCores[s0 * 256];
    int mcurlog = 2;
    float* dst = buf0;
    for (int step = 1; step < nm; ++step) {
        const float* core = &sCores[(s0 + step) * 256];
        const int moutlog = mcurlog + 2;
        const int mout    = 1 << moutlog;
        const int total   = 64 << moutlog;
        const bool last   = (step == nm - 1);
        for (int e = tid; e < total; e += 256) {
            int b  = e & 7;
            int im = (e >> 3) & (mout - 1);
            int a  = e >> (3 + moutlog);
            int i  = im >> 2, mm = im & 3;
            float s = 0.f;
#pragma unroll
            for (int c = 0; c < 8; ++c)
                s = fmaf(src[((a << mcurlog) + i) * 8 + c],
                         core[(c * 4 + mm) * 8 + b], s);
            if (last) ws[wout + e] = s;
            else      dst[e]       = s;
        }
        __syncthreads();
        src = dst;
        dst = (dst == buf0) ? buf1 : buf0;
        mcurlog = moutlog;
    }
}

// bit-interleave: c -> even bit positions, r -> odd bit positions
__device__ __forceinline__ int ilv(int r, int c, int nb) {
    int v = 0;
    for (int t = 0; t < nb; ++t)
        v |= (((c >> t) & 1) << (2 * t)) | (((r >> t) & 1) << (2 * t + 1));
    return v;
}

// ---- K2: build permuted A2 [m][k] and B2t [n][k], split bf16 hi/lo --------
__global__ void k_build(float* __restrict__ ws) {
    int e = blockIdx.x * 256 + threadIdx.x;     // 262144 + 1048576 total
    const float* LA = ws + WS_LA;
    const float* LB = ws + WS_LB;
    const float* RA = ws + WS_RA;
    const float* RB = ws + WS_RB;
    char* wsb = (char*)ws;
    unsigned short* Ahi = (unsigned short*)(wsb + BOFF_AHI);
    unsigned short* Alo = (unsigned short*)(wsb + BOFF_ALO);
    unsigned short* Bhi = (unsigned short*)(wsb + BOFF_BHI);
    unsigned short* Blo = (unsigned short*)(wsb + BOFF_BLO);

    if (e < 262144) {
        int k = e & 63, ch = (e >> 6) & 63, rh = e >> 12;
        int i  = ilv(rh, ch, 6);
        int iA = i >> 4, iB = i & 15;
        int a = k >> 3, b = k & 7;
        float s = 0.f;
#pragma unroll
        for (int c = 0; c < 8; ++c)
            s = fmaf(LA[(a * 256 + iA) * 8 + c], LB[(c * 16 + iB) * 8 + b], s);
        unsigned short h = f2bf(s);
        Ahi[e] = h;
        Alo[e] = f2bf(s - bf2f(h));
    } else {
        int idx = e - 262144;
        int k = idx & 63, n = idx >> 6;
        int rl = n >> 7, cl = n & 127;
        int j  = ilv(rl, cl, 7);
        int jA = j >> 6, jB = j & 63;
        int a = k >> 3, b = k & 7;
        float s = 0.f;
#pragma unroll
        for (int c = 0; c < 8; ++c)
            s = fmaf(RA[(b * 256 + jA) * 8 + c], RB[(c * 64 + jB) * 8 + a], s);
        unsigned short h = f2bf(s);
        Bhi[idx] = h;
        Blo[idx] = f2bf(s - bf2f(h));
    }
}

// ---- K3: 32x32x16 MFMA GEMM, direct full-line stores ----------------------
__global__ __launch_bounds__(256, 3) void k_out3(const float* __restrict__ ws,
                                                 float* __restrict__ out) {
    const char* wsb = (const char*)ws;
    const unsigned short* Ahi = (const unsigned short*)(wsb + BOFF_AHI);
    const unsigned short* Alo = (const unsigned short*)(wsb + BOFF_ALO);
    const unsigned short* Bhi = (const unsigned short*)(wsb + BOFF_BHI);
    const unsigned short* Blo = (const unsigned short*)(wsb + BOFF_BLO);

    const int tid  = threadIdx.x;
    const int lane = tid & 63;
    const int w    = tid >> 6;          // wave 0..3
    const int mb   = blockIdx.x >> 5;   // 0..63 : m rows [mb*64, +64)
    const int nbb  = blockIdx.x & 31;   // 0..31 : n cols [nbb*512, +512)
    const int l31  = lane & 31;
    const int hi   = lane >> 5;         // 0/1

    // A fragments: 2 m-tiles x 4 k-steps, hi/lo. operand: row=lane&31,
    // k = kk*16 + hi*8 + j  -> 16B at (row*64 + kk*16 + hi*8) ushorts.
    bf16x8 Af0h[4], Af0l[4], Af1h[4], Af1l[4];
    {
        const int m0 = mb * 64 + l31;
        const int m1 = m0 + 32;
#pragma unroll
        for (int kk = 0; kk < 4; ++kk) {
            const int o = kk * 16 + hi * 8;
            Af0h[kk] = *(const bf16x8*)(Ahi + m0 * 64 + o);
            Af0l[kk] = *(const bf16x8*)(Alo + m0 * 64 + o);
            Af1h[kk] = *(const bf16x8*)(Ahi + m1 * 64 + o);
            Af1l[kk] = *(const bf16x8*)(Alo + m1 * 64 + o);
        }
    }

#pragma unroll 1
    for (int i = 0; i < 4; ++i) {
        const int nt = i * 4 + w;               // 16 n-tiles of 32
        const int n0 = nbb * 512 + nt * 32;
        const int nrow = n0 + l31;

        bf16x8 Bfh[4], Bfl[4];
#pragma unroll
        for (int kk = 0; kk < 4; ++kk) {
            const int o = kk * 16 + hi * 8;
            Bfh[kk] = *(const bf16x8*)(Bhi + nrow * 64 + o);
            Bfl[kk] = *(const bf16x8*)(Blo + nrow * 64 + o);
        }

        f32x16 acc0 = {0,0,0,0,0,0,0,0,0,0,0,0,0,0,0,0};
        f32x16 acc1 = {0,0,0,0,0,0,0,0,0,0,0,0,0,0,0,0};
#pragma unroll
        for (int kk = 0; kk < 4; ++kk) {
            acc0 = __builtin_amdgcn_mfma_f32_32x32x16_bf16(Af0h[kk], Bfh[kk], acc0, 0, 0, 0);
            acc1 = __builtin_amdgcn_mfma_f32_32x32x16_bf16(Af1h[kk], Bfh[kk], acc1, 0, 0, 0);
            acc0 = __builtin_amdgcn_mfma_f32_32x32x16_bf16(Af0h[kk], Bfl[kk], acc0, 0, 0, 0);
            acc1 = __builtin_amdgcn_mfma_f32_32x32x16_bf16(Af1h[kk], Bfl[kk], acc1, 0, 0, 0);
            acc0 = __builtin_amdgcn_mfma_f32_32x32x16_bf16(Af0l[kk], Bfh[kk], acc0, 0, 0, 0);
            acc1 = __builtin_amdgcn_mfma_f32_32x32x16_bf16(Af1l[kk], Bfh[kk], acc1, 0, 0, 0);
        }

        // store: m = mb*64 + mt*32 + drow, drow = (r&3)+8*(r>>2)+4*hi
        //        n = n0 + (lane&31) -> rl = n0>>7, cl = (n0&127)+(lane&31)
        const int rl  = n0 >> 7;
        const int clb = n0 & 127;
        float* __restrict__ obase =
            out + (((size_t)(mb * 128 + rl)) << 13) + clb + l31 + (size_t)hi * 512;
#pragma unroll
        for (int r = 0; r < 16; ++r) {
            const int drow = (r & 3) + 8 * (r >> 2);
            obase[(size_t)drow * 128]        = acc0[r];
            obase[(size_t)(drow + 32) * 128] = acc1[r];
        }
    }
}

// ---------------------------------------------------------------------------
extern "C" void kernel_launch(void* const* d_in, const int* in_sizes, int n_in,
                              void* d_out, int out_size, void* d_ws, size_t ws_size,
                              hipStream_t stream) {
    const float* bw    = (const float*)d_in[0];   // (13, 32)
    const float* basis = (const float*)d_in[1];   // (32, 8, 4, 8)
    const float* ra    = (const float*)d_in[2];   // (13, 8)
    float* out = (float*)d_out;                   // (8192, 8192) f32
    float* ws  = (float*)d_ws;

    k_chains<<<4,    256, 0, stream>>>(bw, basis, ra, ws);
    k_build <<<5120, 256, 0, stream>>>(ws);
    k_out3  <<<2048, 256, 0, stream>>>(ws, out);
}